// Round 1
// baseline (1840.741 us; speedup 1.0000x reference)
//
#include <hip/hip_runtime.h>
#include <math.h>

// Problem constants
#define BB   16
#define CC   256
#define HW   1024          // 32*32
#define NN   16384         // BB*HW tokens
#define DD   256           // dim
#define KK   8192          // codes
#define ZQ_SIZE 4194304    // 16*256*1024
// d_out layout: [z_q: 4194304][loss: 1][idx-as-float: 16384]

// ---------------------------------------------------------------------------
// Kernel 1: wsq[k] = sum_d W[k][d]^2.  One wave per row, 4 rows per block.
__global__ __launch_bounds__(256) void wsq_kernel(const float* __restrict__ W,
                                                  float* __restrict__ wsq) {
    const int lane = threadIdx.x & 63;
    const int k = blockIdx.x * 4 + (threadIdx.x >> 6);
    float4 v = *(const float4*)(W + (size_t)k * DD + lane * 4);
    float s = v.x * v.x + v.y * v.y + v.z * v.z + v.w * v.w;
    #pragma unroll
    for (int off = 32; off; off >>= 1) s += __shfl_down(s, off);
    if (lane == 0) wsq[k] = s;
}

// ---------------------------------------------------------------------------
// Kernel 2: transpose + l2-normalize.  Block = (b, 64-hw chunk).
// z[b][c][hw] -> zn[n][d] row-major (n = b*1024+hw, d = c), znsq[n] = |zn_n|^2.
__global__ __launch_bounds__(256) void normalize_kernel(const float* __restrict__ z,
                                                        float* __restrict__ zn,
                                                        float* __restrict__ znsq) {
    __shared__ float tile[64][257];
    __shared__ float s_nrm[64];
    const int t   = threadIdx.x;
    const int b   = blockIdx.x >> 4;
    const int hw0 = (blockIdx.x & 15) * 64;

    #pragma unroll 8
    for (int cg = 0; cg < 64; ++cg) {
        int c  = cg * 4 + (t >> 6);
        int hw = t & 63;
        tile[hw][c] = z[((size_t)(b * CC + c) << 10) + hw0 + hw];
    }
    __syncthreads();
    if (t < 64) {
        float s = 0.f;
        #pragma unroll 8
        for (int c = 0; c < 256; ++c) { float v = tile[t][c]; s += v * v; }
        float nrm = sqrtf(s);
        nrm = fmaxf(nrm, 1e-12f);
        s_nrm[t] = nrm;
        znsq[(size_t)b * HW + hw0 + t] = s / (nrm * nrm);
    }
    __syncthreads();
    const size_t n0 = (size_t)b * HW + hw0;
    for (int r = 0; r < 64; ++r) {
        zn[(n0 + r) * DD + t] = tile[r][t] / s_nrm[r];
    }
}

// ---------------------------------------------------------------------------
// Kernel 3: fused GEMM + argmax.  Block handles 64 tokens, scans all 8192 codes.
// score(n,k) = (-znsq[n] - wsq[k]) + 2*dot(zn_n, W_k)   (matches ref fp order)
// Tie-breaking: first max in ascending k (matches jnp.argmax).
__global__ __launch_bounds__(256) void argmax_kernel(const float* __restrict__ zn,
                                                     const float* __restrict__ W,
                                                     const float* __restrict__ wsq,
                                                     const float* __restrict__ znsq,
                                                     int*   __restrict__ bestk_out,
                                                     float* __restrict__ idx_out,
                                                     float* __restrict__ loss_partial) {
    __shared__ float sA[64][68];     // [n_local][d_local]   (pad->aligned, spread banks)
    __shared__ float sB[64][68];     // [d_local][k_local]   transposed W chunk
    __shared__ float sval[64][17];
    __shared__ int   sidx[64][17];

    const int t  = threadIdx.x;
    const int tx = t & 15;           // k-group: 4 consecutive codes
    const int ty = t >> 4;           // n-group: 4 consecutive tokens
    const int n0 = blockIdx.x * 64;

    float best_s[4];
    int   best_k[4];
    #pragma unroll
    for (int i = 0; i < 4; ++i) { best_s[i] = -INFINITY; best_k[i] = 0; }

    float nzq[4];
    #pragma unroll
    for (int i = 0; i < 4; ++i) nzq[i] = -znsq[n0 + ty * 4 + i];

    for (int kt = 0; kt < KK; kt += 64) {
        float acc[4][4];
        #pragma unroll
        for (int i = 0; i < 4; ++i)
            #pragma unroll
            for (int j = 0; j < 4; ++j) acc[i][j] = 0.f;

        for (int dc = 0; dc < DD; dc += 64) {
            // stage A tile: 64 tokens x 64 depths (row-major)
            #pragma unroll
            for (int p = 0; p < 4; ++p) {
                int row = p * 16 + (t >> 4);
                float4 v = *(const float4*)(zn + (size_t)(n0 + row) * DD + dc + (t & 15) * 4);
                *(float4*)(&sA[row][(t & 15) * 4]) = v;
            }
            // stage B tile transposed: sB[d][k] from W[k][d]
            #pragma unroll
            for (int p = 0; p < 4; ++p) {
                int krow = p * 16 + (t >> 4);
                float4 v = *(const float4*)(W + (size_t)(kt + krow) * DD + dc + (t & 15) * 4);
                int dd = (t & 15) * 4;
                sB[dd + 0][krow] = v.x;
                sB[dd + 1][krow] = v.y;
                sB[dd + 2][krow] = v.z;
                sB[dd + 3][krow] = v.w;
            }
            __syncthreads();

            #pragma unroll
            for (int dg = 0; dg < 64; dg += 4) {
                float4 bq[4];
                #pragma unroll
                for (int q = 0; q < 4; ++q) bq[q] = *(const float4*)(&sB[dg + q][tx * 4]);
                #pragma unroll
                for (int i = 0; i < 4; ++i) {
                    float4 av = *(const float4*)(&sA[ty * 4 + i][dg]);
                    acc[i][0] += av.x * bq[0].x + av.y * bq[1].x + av.z * bq[2].x + av.w * bq[3].x;
                    acc[i][1] += av.x * bq[0].y + av.y * bq[1].y + av.z * bq[2].y + av.w * bq[3].y;
                    acc[i][2] += av.x * bq[0].z + av.y * bq[1].z + av.z * bq[2].z + av.w * bq[3].z;
                    acc[i][3] += av.x * bq[0].w + av.y * bq[1].w + av.z * bq[2].w + av.w * bq[3].w;
                }
            }
            __syncthreads();
        }
        // scores for this k-tile; ascending k within thread, strict > keeps first max
        #pragma unroll
        for (int j = 0; j < 4; ++j) {
            int k = kt + tx * 4 + j;
            float wq = wsq[k];
            #pragma unroll
            for (int i = 0; i < 4; ++i) {
                float s = (nzq[i] - wq) + 2.0f * acc[i][j];
                if (s > best_s[i]) { best_s[i] = s; best_k[i] = k; }
            }
        }
    }

    // cross-thread merge (16 tx groups per token); min-idx on exact ties
    #pragma unroll
    for (int i = 0; i < 4; ++i) {
        sval[ty * 4 + i][tx] = best_s[i];
        sidx[ty * 4 + i][tx] = best_k[i];
    }
    __syncthreads();
    if (t < 64) {
        float bs = sval[t][0];
        int   bk = sidx[t][0];
        #pragma unroll
        for (int x = 1; x < 16; ++x) {
            float s = sval[t][x];
            int   k = sidx[t][x];
            if (s > bs || (s == bs && k < bk)) { bs = s; bk = k; }
        }
        int n = n0 + t;
        bestk_out[n] = bk;
        idx_out[n] = (float)bk;
        // |w - z|^2 = znsq + wsq - 2dot = -s_best
        float c = -bs;
        #pragma unroll
        for (int off = 32; off; off >>= 1) c += __shfl_down(c, off);
        if (t == 0) loss_partial[blockIdx.x] = c;
    }
}

// ---------------------------------------------------------------------------
// Kernel 4: z_q[b][c][hw] = W[bestk[b*1024+hw]][c].  Coalesced writes over hw.
__global__ __launch_bounds__(256) void gather_kernel(const float* __restrict__ W,
                                                     const int* __restrict__ bestk,
                                                     float* __restrict__ zq) {
    __shared__ int sbk[64];
    const int t   = threadIdx.x;
    const int b   = blockIdx.x >> 4;
    const int hw0 = (blockIdx.x & 15) * 64;
    if (t < 64) sbk[t] = bestk[b * HW + hw0 + t];
    __syncthreads();
    const int hw  = t & 63;
    const int c0  = (t >> 6) * 4;
    const int row = sbk[hw];
    #pragma unroll
    for (int cg = 0; cg < 16; ++cg) {
        int c = cg * 16 + c0;
        float4 v = *(const float4*)(W + (size_t)row * DD + c);
        size_t base = ((size_t)(b * CC + c) << 10) + hw0 + hw;
        zq[base]        = v.x;
        zq[base + 1024] = v.y;
        zq[base + 2048] = v.z;
        zq[base + 3072] = v.w;
    }
}

// ---------------------------------------------------------------------------
// Kernel 5: final loss = BETA * sum(partials) / (N*D)
__global__ __launch_bounds__(256) void loss_final_kernel(const float* __restrict__ partials,
                                                         float* __restrict__ out_loss) {
    __shared__ float wsum[4];
    const int t = threadIdx.x;
    float v = partials[t];
    #pragma unroll
    for (int off = 32; off; off >>= 1) v += __shfl_down(v, off);
    if ((t & 63) == 0) wsum[t >> 6] = v;
    __syncthreads();
    if (t == 0) {
        float tot = wsum[0] + wsum[1] + wsum[2] + wsum[3];
        *out_loss = 0.25f * (tot / (float)ZQ_SIZE);
    }
}

// ---------------------------------------------------------------------------
extern "C" void kernel_launch(void* const* d_in, const int* in_sizes, int n_in,
                              void* d_out, int out_size, void* d_ws, size_t ws_size,
                              hipStream_t stream) {
    const float* z = (const float*)d_in[0];   // [16,256,32,32]
    const float* W = (const float*)d_in[1];   // [8192,256]

    float* out   = (float*)d_out;
    float* zq    = out;                 // 4194304
    float* loss  = out + ZQ_SIZE;       // 1
    float* idxf  = out + ZQ_SIZE + 1;   // 16384 (idx as float)

    float* ws       = (float*)d_ws;
    float* zn       = ws;                        // N*D   = 4194304 floats
    float* znsq     = zn + (size_t)NN * DD;      // N     = 16384
    float* wsqv     = znsq + NN;                 // K     = 8192
    int*   bestk    = (int*)(wsqv + KK);         // N     = 16384
    float* partials = (float*)(bestk + NN);      // 256

    wsq_kernel      <<<KK / 4, 256, 0, stream>>>(W, wsqv);
    normalize_kernel<<<BB * 16, 256, 0, stream>>>(z, zn, znsq);
    argmax_kernel   <<<NN / 64, 256, 0, stream>>>(zn, W, wsqv, znsq, bestk, idxf, partials);
    gather_kernel   <<<BB * 16, 256, 0, stream>>>(W, bestk, zq);
    loss_final_kernel<<<1, 256, 0, stream>>>(partials, loss);
}

// Round 2
// 393.429 us; speedup vs baseline: 4.6787x; 4.6787x over previous
//
#include <hip/hip_runtime.h>
#include <math.h>

// Problem constants
#define BB   16
#define CC   256
#define HW   1024          // 32*32
#define NN   16384         // BB*HW tokens
#define DD   256           // dim
#define KK   8192          // codes
#define ZQ_SIZE 4194304    // 16*256*1024
#define MARGIN 0.03f       // bf16 scoring error envelope (worst-case bound 0.0156)
#define CAP 16             // candidate-group list capacity per token

typedef __attribute__((ext_vector_type(8))) short short8;  // 8 bf16 (4 VGPRs)
typedef __attribute__((ext_vector_type(4))) float f32x4;

static __device__ inline unsigned short f2bf(float x) {
    unsigned int u = __float_as_uint(x);
    unsigned int r = (u + 0x7fff + ((u >> 16) & 1)) >> 16;   // RNE
    return (unsigned short)r;
}

// ---------------------------------------------------------------------------
// Kernel 1: wsq[k] = sum_d W[k][d]^2 (fp32). One wave per row, 4 rows/block.
__global__ __launch_bounds__(256) void wsq_kernel(const float* __restrict__ W,
                                                  float* __restrict__ wsq) {
    const int lane = threadIdx.x & 63;
    const int k = blockIdx.x * 4 + (threadIdx.x >> 6);
    float4 v = *(const float4*)(W + (size_t)k * DD + lane * 4);
    float s = v.x * v.x + v.y * v.y + v.z * v.z + v.w * v.w;
    #pragma unroll
    for (int off = 32; off; off >>= 1) s += __shfl_down(s, off);
    if (lane == 0) wsq[k] = s;
}

// ---------------------------------------------------------------------------
// Kernel 2: transpose + l2-normalize; emits fp32 zn[n][d], znsq[n], and the
// bf16 tiled blob zb: element (n = mt*128+r, d = dc*64+c*8+j) lives at
// zb[(mt*4+dc)*8192 + (c*128 + r)*8 + j]  (exact LDS image for the MFMA stage)
__global__ __launch_bounds__(256) void normalize_kernel(const float* __restrict__ z,
                                                        float* __restrict__ zn,
                                                        float* __restrict__ znsq,
                                                        unsigned short* __restrict__ zb) {
    __shared__ float tile[64][257];
    __shared__ float s_nrm[64];
    const int t   = threadIdx.x;
    const int b   = blockIdx.x >> 4;
    const int hw0 = (blockIdx.x & 15) * 64;

    #pragma unroll 8
    for (int cg = 0; cg < 64; ++cg) {
        int c  = cg * 4 + (t >> 6);
        int hw = t & 63;
        tile[hw][c] = z[((size_t)(b * CC + c) << 10) + hw0 + hw];
    }
    __syncthreads();
    if (t < 64) {
        float s = 0.f;
        #pragma unroll 8
        for (int c = 0; c < 256; ++c) { float v = tile[t][c]; s += v * v; }
        float nrm = sqrtf(s);
        nrm = fmaxf(nrm, 1e-12f);
        s_nrm[t] = nrm;
        znsq[(size_t)b * HW + hw0 + t] = s / (nrm * nrm);
    }
    __syncthreads();
    const int n0 = b * HW + hw0;           // multiple of 64
    // fp32 zn write (coalesced over depth t)
    for (int r = 0; r < 64; ++r) {
        zn[(size_t)(n0 + r) * DD + t] = tile[r][t] / s_nrm[r];
    }
    // bf16 blob write: wave (t>>6) handles c-combo, lane = token row
    const int r    = t & 63;
    const int mt   = n0 >> 7;
    const int rg   = (n0 & 127) + r;       // row within m-tile
    const float nrm = s_nrm[r];
    #pragma unroll
    for (int loop = 0; loop < 8; ++loop) {
        int comb = loop * 4 + (t >> 6);    // 0..31
        int dc = comb >> 3, c = comb & 7;
        int d0 = dc * 64 + c * 8;
        uint4 out;
        unsigned int w0, w1, w2, w3;
        {
            unsigned short l0 = f2bf(tile[r][d0 + 0] / nrm), h0 = f2bf(tile[r][d0 + 1] / nrm);
            unsigned short l1 = f2bf(tile[r][d0 + 2] / nrm), h1 = f2bf(tile[r][d0 + 3] / nrm);
            unsigned short l2 = f2bf(tile[r][d0 + 4] / nrm), h2 = f2bf(tile[r][d0 + 5] / nrm);
            unsigned short l3 = f2bf(tile[r][d0 + 6] / nrm), h3 = f2bf(tile[r][d0 + 7] / nrm);
            w0 = (unsigned int)l0 | ((unsigned int)h0 << 16);
            w1 = (unsigned int)l1 | ((unsigned int)h1 << 16);
            w2 = (unsigned int)l2 | ((unsigned int)h2 << 16);
            w3 = (unsigned int)l3 | ((unsigned int)h3 << 16);
        }
        out.x = w0; out.y = w1; out.z = w2; out.w = w3;
        *(uint4*)(zb + (size_t)(mt * 4 + dc) * 8192 + (size_t)(c * 128 + rg) * 8) = out;
    }
}

// ---------------------------------------------------------------------------
// Kernel 3: W -> bf16 tiled blob wb (same layout, k-tiles of 128 codes).
__global__ __launch_bounds__(256) void wb_convert_kernel(const float* __restrict__ W,
                                                         unsigned short* __restrict__ wb) {
    const int ch = blockIdx.x * 256 + threadIdx.x;     // chunk id, 0..262143
    const int blob = ch >> 10;
    const int c = (ch >> 7) & 7;
    const int r = ch & 127;
    const int kt = blob >> 2, dc = blob & 3;
    const int k = kt * 128 + r;
    const int d0 = dc * 64 + c * 8;
    const float4 v0 = *(const float4*)(W + (size_t)k * DD + d0);
    const float4 v1 = *(const float4*)(W + (size_t)k * DD + d0 + 4);
    uint4 out;
    out.x = (unsigned int)f2bf(v0.x) | ((unsigned int)f2bf(v0.y) << 16);
    out.y = (unsigned int)f2bf(v0.z) | ((unsigned int)f2bf(v0.w) << 16);
    out.z = (unsigned int)f2bf(v1.x) | ((unsigned int)f2bf(v1.y) << 16);
    out.w = (unsigned int)f2bf(v1.z) | ((unsigned int)f2bf(v1.w) << 16);
    *(uint4*)(wb + (size_t)ch * 8) = out;
}

// ---------------------------------------------------------------------------
// Kernel 4: MFMA scorer. Block = 128 tokens x 128 codes; writes per-token
// per-32-code-group max of t = 2*dot_bf16 - wsq[k]  -> cmax[n][256].
__global__ __launch_bounds__(256) void score_kernel(const unsigned short* __restrict__ zb,
                                                    const unsigned short* __restrict__ wb,
                                                    const float* __restrict__ wsqv,
                                                    float* __restrict__ cmax) {
    __shared__ unsigned short sA[8192];   // 16 KB: [8 chunks][128 rows][8 bf16]
    __shared__ unsigned short sB[8192];   // 16 KB
    __shared__ float rowbuf[128][4];

    const int tid  = threadIdx.x;
    const int w    = tid >> 6;
    const int lane = tid & 63;
    const int wr   = w >> 1, wc = w & 1;
    const int q    = lane >> 4, c15 = lane & 15;
    const int kt   = blockIdx.x & 63;
    const int mt   = blockIdx.x >> 6;

    f32x4 acc[4][4];
    #pragma unroll
    for (int fi = 0; fi < 4; ++fi)
        #pragma unroll
        for (int fj = 0; fj < 4; ++fj)
            acc[fi][fj] = (f32x4){0.f, 0.f, 0.f, 0.f};

    for (int dc = 0; dc < 4; ++dc) {
        const unsigned short* gA = zb + (size_t)(mt * 4 + dc) * 8192;
        const unsigned short* gB = wb + (size_t)(kt * 4 + dc) * 8192;
        #pragma unroll
        for (int i = 0; i < 4; ++i) {
            int eo = ((w * 4 + i) << 9);            // element offset (512 per issue)
            __builtin_amdgcn_global_load_lds(
                (const __attribute__((address_space(1))) void*)(gA + eo + lane * 8),
                (__attribute__((address_space(3))) void*)(sA + eo), 16, 0, 0);
            __builtin_amdgcn_global_load_lds(
                (const __attribute__((address_space(1))) void*)(gB + eo + lane * 8),
                (__attribute__((address_space(3))) void*)(sB + eo), 16, 0, 0);
        }
        __syncthreads();
        #pragma unroll
        for (int ks = 0; ks < 2; ++ks) {
            short8 af[4], bfr[4];
            const int ca = (ks * 4 + q) * 128;
            #pragma unroll
            for (int f = 0; f < 4; ++f) {
                af[f]  = *(const short8*)(sA + (size_t)(ca + wr * 64 + f * 16 + c15) * 8);
                bfr[f] = *(const short8*)(sB + (size_t)(ca + wc * 64 + f * 16 + c15) * 8);
            }
            #pragma unroll
            for (int fi = 0; fi < 4; ++fi)
                #pragma unroll
                for (int fj = 0; fj < 4; ++fj)
                    acc[fi][fj] = __builtin_amdgcn_mfma_f32_16x16x32_bf16(
                        af[fi], bfr[fj], acc[fi][fj], 0, 0, 0);
        }
        __syncthreads();
    }

    // epilogue: per-row (token) max over each 32-code group
    float wsqc[4];
    #pragma unroll
    for (int fj = 0; fj < 4; ++fj)
        wsqc[fj] = wsqv[kt * 128 + wc * 64 + fj * 16 + c15];

    #pragma unroll
    for (int fi = 0; fi < 4; ++fi) {
        float vmx[2][4];
        #pragma unroll
        for (int fjp = 0; fjp < 2; ++fjp) {
            #pragma unroll
            for (int rg = 0; rg < 4; ++rg) {
                float a0 = 2.0f * acc[fi][2 * fjp][rg]     - wsqc[2 * fjp];
                float a1 = 2.0f * acc[fi][2 * fjp + 1][rg] - wsqc[2 * fjp + 1];
                float v = fmaxf(a0, a1);
                v = fmaxf(v, __shfl_xor(v, 1));
                v = fmaxf(v, __shfl_xor(v, 2));
                v = fmaxf(v, __shfl_xor(v, 4));
                v = fmaxf(v, __shfl_xor(v, 8));
                vmx[fjp][rg] = v;
            }
        }
        if (c15 < 4) {
            int row = wr * 64 + fi * 16 + q * 4 + c15;
            rowbuf[row][wc * 2 + 0] = vmx[0][c15];
            rowbuf[row][wc * 2 + 1] = vmx[1][c15];
        }
    }
    __syncthreads();
    {
        int row = tid >> 1, half = tid & 1;
        float2 v2 = make_float2(rowbuf[row][half * 2], rowbuf[row][half * 2 + 1]);
        *(float2*)(cmax + (size_t)(mt * 128 + row) * 256 + kt * 4 + half * 2) = v2;
    }
}

// ---------------------------------------------------------------------------
// Kernel 5: per-token candidate selection + exact fp32 rescore + outputs.
// One wave per token (4 tokens per block).
__global__ __launch_bounds__(256) void select_kernel(const float* __restrict__ zn,
                                                     const float* __restrict__ W,
                                                     const float* __restrict__ wsqv,
                                                     const float* __restrict__ znsq,
                                                     const float* __restrict__ cmax,
                                                     int*   __restrict__ bestk_out,
                                                     float* __restrict__ idx_out,
                                                     float* __restrict__ partials) {
    __shared__ float znrow[4][256];
    __shared__ int   cand[4][CAP];
    __shared__ int   cnt[4];
    __shared__ float wacc[4];

    const int t = threadIdx.x;
    const int wv = t >> 6, lane = t & 63;
    const int n = blockIdx.x * 4 + wv;

    // stage zn row into LDS
    *(float4*)(&znrow[wv][lane * 4]) = *(const float4*)(zn + (size_t)n * DD + lane * 4);
    if (lane == 0) cnt[wv] = 0;

    // group maxima and global max
    float4 c4 = *(const float4*)(cmax + (size_t)n * 256 + lane * 4);
    float lm = fmaxf(fmaxf(c4.x, c4.y), fmaxf(c4.z, c4.w));
    #pragma unroll
    for (int off = 1; off <= 32; off <<= 1) lm = fmaxf(lm, __shfl_xor(lm, off));
    const float thresh = lm - MARGIN;

    float myg[4] = {c4.x, c4.y, c4.z, c4.w};
    #pragma unroll
    for (int j = 0; j < 4; ++j) {
        if (myg[j] >= thresh) {
            int p = atomicAdd(&cnt[wv], 1);
            if (p < CAP) cand[wv][p] = lane * 4 + j;
        }
    }
    __syncthreads();

    const float zsq = znsq[n];
    const int count = cnt[wv];
    float best_s = -INFINITY;
    int   best_k = 0;

    const int code_off = lane >> 1;     // 0..31 within group
    const int part     = lane & 1;      // depth half

    if (count <= CAP) {
        for (int ci = 0; ci < count; ++ci) {
            int g = cand[wv][ci];
            int k = g * 32 + code_off;
            const float4* wrp = (const float4*)(W + (size_t)k * DD + part * 128);
            const float4* zrp = (const float4*)(&znrow[wv][part * 128]);
            float d = 0.f;
            #pragma unroll
            for (int jj = 0; jj < 32; ++jj) {
                float4 a = zrp[jj], b = wrp[jj];
                d += a.x * b.x + a.y * b.y + a.z * b.z + a.w * b.w;
            }
            d += __shfl_xor(d, 1);
            float s = (-zsq - wsqv[k]) + 2.0f * d;
            if (s > best_s || (s == best_s && k < best_k)) { best_s = s; best_k = k; }
        }
    } else {
        for (int g = 0; g < 256; ++g) {
            int k = g * 32 + code_off;
            const float4* wrp = (const float4*)(W + (size_t)k * DD + part * 128);
            const float4* zrp = (const float4*)(&znrow[wv][part * 128]);
            float d = 0.f;
            #pragma unroll
            for (int jj = 0; jj < 32; ++jj) {
                float4 a = zrp[jj], b = wrp[jj];
                d += a.x * b.x + a.y * b.y + a.z * b.z + a.w * b.w;
            }
            d += __shfl_xor(d, 1);
            float s = (-zsq - wsqv[k]) + 2.0f * d;
            if (s > best_s || (s == best_s && k < best_k)) { best_s = s; best_k = k; }
        }
    }

    // merge across the wave (max, min-k tie-break)
    #pragma unroll
    for (int off = 1; off <= 32; off <<= 1) {
        float os = __shfl_xor(best_s, off);
        int   ok = __shfl_xor(best_k, off);
        if (os > best_s || (os == best_s && ok < best_k)) { best_s = os; best_k = ok; }
    }
    if (lane == 0) {
        bestk_out[n] = best_k;
        idx_out[n]   = (float)best_k;
        wacc[wv]     = -best_s;          // |w-z|^2 = -(score)
    }
    __syncthreads();
    if (t == 0) partials[blockIdx.x] = wacc[0] + wacc[1] + wacc[2] + wacc[3];
}

// ---------------------------------------------------------------------------
// Kernel 6: z_q[b][c][hw] = W[bestk[b*1024+hw]][c].  Coalesced writes over hw.
__global__ __launch_bounds__(256) void gather_kernel(const float* __restrict__ W,
                                                     const int* __restrict__ bestk,
                                                     float* __restrict__ zq) {
    __shared__ int sbk[64];
    const int t   = threadIdx.x;
    const int b   = blockIdx.x >> 4;
    const int hw0 = (blockIdx.x & 15) * 64;
    if (t < 64) sbk[t] = bestk[b * HW + hw0 + t];
    __syncthreads();
    const int hw  = t & 63;
    const int c0  = (t >> 6) * 4;
    const int row = sbk[hw];
    #pragma unroll
    for (int cg = 0; cg < 16; ++cg) {
        int c = cg * 16 + c0;
        float4 v = *(const float4*)(W + (size_t)row * DD + c);
        size_t base = ((size_t)(b * CC + c) << 10) + hw0 + hw;
        zq[base]        = v.x;
        zq[base + 1024] = v.y;
        zq[base + 2048] = v.z;
        zq[base + 3072] = v.w;
    }
}

// ---------------------------------------------------------------------------
// Kernel 7: final loss = BETA * sum(partials) / (N*D).  4096 partials.
__global__ __launch_bounds__(256) void loss_final_kernel(const float* __restrict__ partials,
                                                         float* __restrict__ out_loss) {
    __shared__ float wsum[4];
    const int t = threadIdx.x;
    float v = 0.f;
    #pragma unroll
    for (int i = 0; i < 16; ++i) v += partials[t + i * 256];
    #pragma unroll
    for (int off = 32; off; off >>= 1) v += __shfl_down(v, off);
    if ((t & 63) == 0) wsum[t >> 6] = v;
    __syncthreads();
    if (t == 0) {
        float tot = wsum[0] + wsum[1] + wsum[2] + wsum[3];
        *out_loss = 0.25f * (tot / (float)ZQ_SIZE);
    }
}

// ---------------------------------------------------------------------------
extern "C" void kernel_launch(void* const* d_in, const int* in_sizes, int n_in,
                              void* d_out, int out_size, void* d_ws, size_t ws_size,
                              hipStream_t stream) {
    const float* z = (const float*)d_in[0];   // [16,256,32,32]
    const float* W = (const float*)d_in[1];   // [8192,256]

    float* out   = (float*)d_out;
    float* zq    = out;                 // 4194304
    float* loss  = out + ZQ_SIZE;       // 1
    float* idxf  = out + ZQ_SIZE + 1;   // 16384 (idx as float)

    float* ws       = (float*)d_ws;
    float* zn       = ws;                        // 4194304 f
    float* znsq     = zn + (size_t)NN * DD;      // 16384 f
    float* wsqv     = znsq + NN;                 // 8192 f
    int*   bestk    = (int*)(wsqv + KK);         // 16384 i
    float* partials = (float*)(bestk + NN);      // 4096 f
    unsigned short* zb = (unsigned short*)(partials + 4096);  // 4194304 bf16
    unsigned short* wb = zb + (size_t)NN * DD;                // 2097152 bf16
    float* cmax     = (float*)(wb + (size_t)KK * DD);         // 4194304 f (16 MB)

    wsq_kernel       <<<KK / 4, 256, 0, stream>>>(W, wsqv);
    normalize_kernel <<<BB * 16, 256, 0, stream>>>(z, zn, znsq, zb);
    wb_convert_kernel<<<KK * DD / 8 / 256, 256, 0, stream>>>(W, wb);
    score_kernel     <<<(NN / 128) * (KK / 128), 256, 0, stream>>>(zb, wb, wsqv, cmax);
    select_kernel    <<<NN / 4, 256, 0, stream>>>(zn, W, wsqv, znsq, cmax, bestk, idxf, partials);
    gather_kernel    <<<BB * 16, 256, 0, stream>>>(W, bestk, zq);
    loss_final_kernel<<<1, 256, 0, stream>>>(partials, loss);
}